// Round 1
// baseline (1587.030 us; speedup 1.0000x reference)
//
#include <hip/hip_runtime.h>

#define Bb 64
#define Nn 128
#define Ee 2048
#define Hh 256
#define Ll 6
#define TN 8192
#define TE 131072
#define EDGE 50
#define EKPAD 64

typedef __attribute__((ext_vector_type(4))) float f32x4;
typedef __attribute__((ext_vector_type(8))) __bf16 bf16x8;
typedef __attribute__((ext_vector_type(8))) unsigned short ushort8;

__device__ inline float b2f(unsigned short u) {
    union { unsigned u; float f; } v; v.u = ((unsigned)u) << 16; return v.f;
}
__device__ inline unsigned short f2b(float f) {
    union { float f; unsigned u; } v; v.f = f;
    unsigned r = v.u + 0x7fffu + ((v.u >> 16) & 1u);
    return (unsigned short)(r >> 16);
}
__device__ inline float spf(float x) {   // softplus, stable
    return fmaxf(x, 0.f) + log1pf(expf(-fabsf(x)));
}
__device__ inline float sspf(float x) {  // shifted softplus
    return spf(x) - 0.69314718055994530942f;
}

// ---------------- GEMM: C = act(A @ WT^T + bias) ----------------
// A: M x K bf16 row-major.  WT: N x K bf16 row-major (pre-transposed weight).
// OUTMODE 0: write bf16 Cb. 1: write f32 Cf. 2: x-update: Xf += v, Xb = bf16(Xf).
template <int ACT, int OUTMODE>
__global__ __launch_bounds__(256)
void gemm_k(const unsigned short* __restrict__ A,
            const unsigned short* __restrict__ WT,
            const float* __restrict__ bias,
            unsigned short* __restrict__ Cb,
            float* __restrict__ Cf,
            float* __restrict__ Xf,
            unsigned short* __restrict__ Xb,
            int M, int N, int K)
{
    __shared__ unsigned short As[128 * 32];
    __shared__ unsigned short Bs[128 * 32];

    const int tid  = threadIdx.x;
    const int lane = tid & 63;
    const int w    = tid >> 6;          // wave 0..3
    const int wr   = w >> 1, wc = w & 1; // 2x2 wave grid, each wave 64x64
    const int r16  = lane & 15;
    const int kg   = lane >> 4;          // k-group 0..3

    const long brow = (long)blockIdx.y * 128;
    const int  bcol = blockIdx.x * 128;

    const int srow  = tid >> 2;          // 0..63 staging row
    const int scol8 = (tid & 3) * 8;     // staging k-offset (elements)

    f32x4 acc[4][4];
#pragma unroll
    for (int m = 0; m < 4; ++m)
#pragma unroll
        for (int n = 0; n < 4; ++n) acc[m][n] = f32x4{0.f, 0.f, 0.f, 0.f};

    for (int k0 = 0; k0 < K; k0 += 32) {
        // register-staged loads (16B per thread per chunk, 2 chunks per tile)
        ushort8 ra0 = *(const ushort8*)(A  + (brow + srow)       * (long)K + k0 + scol8);
        ushort8 ra1 = *(const ushort8*)(A  + (brow + 64 + srow)  * (long)K + k0 + scol8);
        ushort8 rb0 = *(const ushort8*)(WT + (bcol + srow)       * (long)K + k0 + scol8);
        ushort8 rb1 = *(const ushort8*)(WT + (bcol + 64 + srow)  * (long)K + k0 + scol8);
        __syncthreads();   // previous iteration's LDS reads complete
        *(ushort8*)(As + (srow)      * 32 + scol8) = ra0;
        *(ushort8*)(As + (64 + srow) * 32 + scol8) = ra1;
        *(ushort8*)(Bs + (srow)      * 32 + scol8) = rb0;
        *(ushort8*)(Bs + (64 + srow) * 32 + scol8) = rb1;
        __syncthreads();

        bf16x8 a[4], b[4];
#pragma unroll
        for (int m = 0; m < 4; ++m)
            a[m] = *(const bf16x8*)(As + (wr * 64 + m * 16 + r16) * 32 + kg * 8);
#pragma unroll
        for (int n = 0; n < 4; ++n)
            b[n] = *(const bf16x8*)(Bs + (wc * 64 + n * 16 + r16) * 32 + kg * 8);
#pragma unroll
        for (int m = 0; m < 4; ++m)
#pragma unroll
            for (int n = 0; n < 4; ++n)
                acc[m][n] = __builtin_amdgcn_mfma_f32_16x16x32_bf16(a[m], b[n], acc[m][n], 0, 0, 0);
    }

    // epilogue: C row = (lane>>4)*4 + j, col = lane&15 (m89-verified layout)
#pragma unroll
    for (int m = 0; m < 4; ++m) {
#pragma unroll
        for (int n = 0; n < 4; ++n) {
            const int col = bcol + wc * 64 + n * 16 + r16;
            const float bv = bias[col];
#pragma unroll
            for (int j = 0; j < 4; ++j) {
                const long row = brow + wr * 64 + m * 16 + kg * 4 + j;
                float v = acc[m][n][j] + bv;
                if (ACT) v = sspf(v);
                const long idx = row * (long)N + col;
                if (OUTMODE == 0) {
                    Cb[idx] = f2b(v);
                } else if (OUTMODE == 1) {
                    Cf[idx] = v;
                } else {
                    float nx = Xf[idx] + v;
                    Xf[idx] = nx;
                    Xb[idx] = f2b(nx);
                }
            }
        }
    }
}

// ---------------- small kernels ----------------
__global__ void k_offsets(const int* __restrict__ num_nodes, int* __restrict__ off) {
    __shared__ int s[Bb];
    int t = threadIdx.x;
    s[t] = num_nodes[t];
    __syncthreads();
    for (int d = 1; d < Bb; d <<= 1) {
        int v = (t >= d) ? s[t - d] : 0;
        __syncthreads();
        s[t] += v;
        __syncthreads();
    }
    off[t + 1] = s[t];
    if (t == 0) off[0] = 0;
}

__global__ void k_edgeprep(const int* __restrict__ edges, const int* __restrict__ off,
                           int* __restrict__ gsrc, int* __restrict__ gdst, int* __restrict__ cnt) {
    int ge = blockIdx.x * 256 + threadIdx.x;
    if (ge >= TE) return;
    int b = ge >> 11;                     // E = 2048
    int o = off[b];
    int s = edges[ge * 2 + 0] + o;
    int d = edges[ge * 2 + 1] + o;
    gsrc[ge] = s;
    gdst[ge] = d;
    atomicAdd(&cnt[d], 1);
}

__global__ void k_scan(const int* __restrict__ cnt, int* __restrict__ coff, int* __restrict__ pos) {
    __shared__ int part[1024];
    int t = threadIdx.x;
    int loc[8];
    int s = 0;
#pragma unroll
    for (int j = 0; j < 8; ++j) { loc[j] = cnt[t * 8 + j]; s += loc[j]; }
    part[t] = s;
    __syncthreads();
    for (int d = 1; d < 1024; d <<= 1) {
        int v = (t >= d) ? part[t - d] : 0;
        __syncthreads();
        part[t] += v;
        __syncthreads();
    }
    int base = part[t] - s;   // exclusive
#pragma unroll
    for (int j = 0; j < 8; ++j) {
        int idx = t * 8 + j;
        coff[idx] = base;
        pos[idx]  = base;
        base += loc[j];
    }
    if (t == 1023) coff[TN] = part[1023];
}

__global__ void k_fill(const int* __restrict__ gdst, int* __restrict__ pos, int* __restrict__ eidl) {
    int ge = blockIdx.x * 256 + threadIdx.x;
    if (ge >= TE) return;
    int p = atomicAdd(&pos[gdst[ge]], 1);
    eidl[p] = ge;
}

__global__ void k_rbf(const float* __restrict__ ef, unsigned short* __restrict__ erbf) {
    int gid = blockIdx.x * 256 + threadIdx.x;   // TE * 64
    int ge = gid >> 6, k = gid & 63;
    float v = 0.f;
    if (k < EDGE) {
        float d = ef[ge];
        float t = d - 0.1f * (float)k;
        v = expf(-50.f * t * t);
    }
    erbf[gid] = f2b(v);
}

__global__ void k_embed(const int* __restrict__ nodes, const float* __restrict__ embed,
                        float* __restrict__ x, unsigned short* __restrict__ xb) {
    int gid = blockIdx.x * 256 + threadIdx.x;   // TN * 256
    int i = gid >> 8, c = gid & 255;
    float v = embed[(nodes[i] << 8) + c];
    x[gid] = v;
    xb[gid] = f2b(v);
}

// convert + transpose all weights to bf16 N x K
__global__ void k_wprep(const float* __restrict__ me_w1, const float* __restrict__ me_w2,
                        const float* __restrict__ mn_w1, const float* __restrict__ mn_w2,
                        const float* __restrict__ st_w1, const float* __restrict__ st_w2,
                        const float* __restrict__ ro_w1,
                        unsigned short* __restrict__ me1T, unsigned short* __restrict__ me2T,
                        unsigned short* __restrict__ mn1T, unsigned short* __restrict__ mn2T,
                        unsigned short* __restrict__ st1T, unsigned short* __restrict__ st2T,
                        unsigned short* __restrict__ ro1T) {
    int gid = blockIdx.x * 256 + threadIdx.x;
    const int S1 = Ll * 256 * EKPAD;          // me_w1T (padded K)
    if (gid < S1) {
        int i = gid / (256 * EKPAD);
        int r = gid % (256 * EKPAD);
        int n = r / EKPAD, k = r % EKPAD;
        float v = (k < EDGE) ? me_w1[(i * EDGE + k) * 256 + n] : 0.f;
        me1T[gid] = f2b(v);
        return;
    }
    gid -= S1;
    const int S2 = Ll * 256 * 256;
    const float* srcs[5] = { me_w2, mn_w1, mn_w2, st_w1, st_w2 };
    unsigned short* dsts[5] = { me2T, mn1T, mn2T, st1T, st2T };
#pragma unroll
    for (int q = 0; q < 5; ++q) {
        if (gid < S2) {
            int i = gid >> 16;
            int r = gid & 65535;
            int n = r >> 8, k = r & 255;
            dsts[q][gid] = f2b(srcs[q][(i << 16) + k * 256 + n]);
            return;
        }
        gid -= S2;
    }
    // ro_w1T: 256x256
    int n = gid >> 8, k = gid & 255;
    ro1T[gid] = f2b(ro_w1[k * 256 + n]);
}

__global__ void k_agg(const float* __restrict__ nmsg, const unsigned short* __restrict__ gates,
                      const int* __restrict__ gsrc, const int* __restrict__ coff,
                      const int* __restrict__ eidl, unsigned short* __restrict__ msum) {
    int n = blockIdx.x, c = threadIdx.x;
    float s = 0.f;
    int beg = coff[n], end = coff[n + 1];
    for (int i = beg; i < end; ++i) {
        int e = eidl[i];
        s += nmsg[(gsrc[e] << 8) + c] * b2f(gates[(e << 8) + c]);
    }
    msum[(n << 8) + c] = f2b(s);
}

__global__ void k_readout(const unsigned short* __restrict__ t, const float* __restrict__ w2,
                          const float* __restrict__ b2, const int* __restrict__ num_nodes,
                          const float* __restrict__ evw, const float* __restrict__ evb,
                          float* __restrict__ out) {
    __shared__ float red[256];
    int b = blockIdx.x, tid = threadIdx.x;
    const unsigned short* tb = t + (long)b * Nn * 256;
    float part = 0.f;
    for (int i = tid; i < Nn * 256; i += 256)
        part += b2f(tb[i]) * w2[i & 255];
    red[tid] = part;
    __syncthreads();
    for (int d = 128; d > 0; d >>= 1) {
        if (tid < d) red[tid] += red[tid + d];
        __syncthreads();
    }
    if (tid == 0) {
        float g = red[0] + (float)Nn * b2[0];
        g = g * 2.0f + (-1.5f) * (float)num_nodes[b];
        float z0 = g * evw[0] + evb[0];
        float z1 = g * evw[1] + evb[1];
        float z2 = g * evw[2] + evb[2];
        float z3 = g * evw[3] + evb[3];
        out[b * 4 + 0] = z0;
        out[b * 4 + 1] = spf(z1);
        out[b * 4 + 2] = spf(z2) + 1.f;
        out[b * 4 + 3] = spf(z3);
    }
}

// ---------------- workspace layout ----------------
constexpr size_t al(size_t x) { return (x + 255) & ~(size_t)255; }
constexpr size_t O_OFF  = 0;
constexpr size_t O_GSRC = al(O_OFF + 65 * 4);
constexpr size_t O_GDST = al(O_GSRC + (size_t)TE * 4);
constexpr size_t O_CNT  = al(O_GDST + (size_t)TE * 4);
constexpr size_t O_COFF = al(O_CNT + (size_t)TN * 4);
constexpr size_t O_POS  = al(O_COFF + (size_t)(TN + 1) * 4);
constexpr size_t O_EIDL = al(O_POS + (size_t)TN * 4);
constexpr size_t O_ERBF = al(O_EIDL + (size_t)TE * 4);
constexpr size_t O_ME1T = al(O_ERBF + (size_t)TE * EKPAD * 2);
constexpr size_t O_ME2T = al(O_ME1T + (size_t)Ll * 256 * EKPAD * 2);
constexpr size_t O_MN1T = al(O_ME2T + (size_t)Ll * 256 * 256 * 2);
constexpr size_t O_MN2T = al(O_MN1T + (size_t)Ll * 256 * 256 * 2);
constexpr size_t O_ST1T = al(O_MN2T + (size_t)Ll * 256 * 256 * 2);
constexpr size_t O_ST2T = al(O_ST1T + (size_t)Ll * 256 * 256 * 2);
constexpr size_t O_RO1T = al(O_ST2T + (size_t)Ll * 256 * 256 * 2);
constexpr size_t O_X    = al(O_RO1T + (size_t)256 * 256 * 2);
constexpr size_t O_XB   = al(O_X + (size_t)TN * 256 * 4);
constexpr size_t O_TMPB = al(O_XB + (size_t)TN * 256 * 2);
constexpr size_t O_NMSG = al(O_TMPB + (size_t)TN * 256 * 2);
constexpr size_t O_MSUM = al(O_NMSG + (size_t)TN * 256 * 4);
constexpr size_t O_TEDG = al(O_MSUM + (size_t)TN * 256 * 2);
constexpr size_t O_GATE = al(O_TEDG + (size_t)TE * 256 * 2);
constexpr size_t WS_NEED = al(O_GATE + (size_t)TE * 256 * 2);

extern "C" void kernel_launch(void* const* d_in, const int* in_sizes, int n_in,
                              void* d_out, int out_size, void* d_ws, size_t ws_size,
                              hipStream_t stream) {
    if (ws_size < WS_NEED) return;   // leaves d_out zeroed -> distinguishable failure signature

    const int*   nodes     = (const int*)d_in[0];
    const int*   num_nodes = (const int*)d_in[1];
    const int*   edges     = (const int*)d_in[2];
    const float* efeat     = (const float*)d_in[3];
    const float* embed     = (const float*)d_in[5];
    const float* me_w1 = (const float*)d_in[6],  *me_b1 = (const float*)d_in[7];
    const float* me_w2 = (const float*)d_in[8],  *me_b2 = (const float*)d_in[9];
    const float* mn_w1 = (const float*)d_in[10], *mn_b1 = (const float*)d_in[11];
    const float* mn_w2 = (const float*)d_in[12], *mn_b2 = (const float*)d_in[13];
    const float* st_w1 = (const float*)d_in[14], *st_b1 = (const float*)d_in[15];
    const float* st_w2 = (const float*)d_in[16], *st_b2 = (const float*)d_in[17];
    const float* ro_w1 = (const float*)d_in[18], *ro_b1 = (const float*)d_in[19];
    const float* ro_w2 = (const float*)d_in[20], *ro_b2 = (const float*)d_in[21];
    const float* ev_w  = (const float*)d_in[22], *ev_b  = (const float*)d_in[23];

    char* ws = (char*)d_ws;
    int* off  = (int*)(ws + O_OFF);
    int* gsrc = (int*)(ws + O_GSRC);
    int* gdst = (int*)(ws + O_GDST);
    int* cnt  = (int*)(ws + O_CNT);
    int* coff = (int*)(ws + O_COFF);
    int* pos  = (int*)(ws + O_POS);
    int* eidl = (int*)(ws + O_EIDL);
    unsigned short* erbf = (unsigned short*)(ws + O_ERBF);
    unsigned short* me1T = (unsigned short*)(ws + O_ME1T);
    unsigned short* me2T = (unsigned short*)(ws + O_ME2T);
    unsigned short* mn1T = (unsigned short*)(ws + O_MN1T);
    unsigned short* mn2T = (unsigned short*)(ws + O_MN2T);
    unsigned short* st1T = (unsigned short*)(ws + O_ST1T);
    unsigned short* st2T = (unsigned short*)(ws + O_ST2T);
    unsigned short* ro1T = (unsigned short*)(ws + O_RO1T);
    float*          x    = (float*)(ws + O_X);
    unsigned short* xb   = (unsigned short*)(ws + O_XB);
    unsigned short* tmpb = (unsigned short*)(ws + O_TMPB);
    float*          nmsg = (float*)(ws + O_NMSG);
    unsigned short* msum = (unsigned short*)(ws + O_MSUM);
    unsigned short* tedg = (unsigned short*)(ws + O_TEDG);
    unsigned short* gate = (unsigned short*)(ws + O_GATE);
    float* out = (float*)d_out;

    hipMemsetAsync(cnt, 0, TN * 4, stream);
    k_offsets<<<1, Bb, 0, stream>>>(num_nodes, off);
    k_edgeprep<<<TE / 256, 256, 0, stream>>>(edges, off, gsrc, gdst, cnt);
    k_scan<<<1, 1024, 0, stream>>>(cnt, coff, pos);
    k_fill<<<TE / 256, 256, 0, stream>>>(gdst, pos, eidl);
    k_rbf<<<(TE * EKPAD) / 256, 256, 0, stream>>>(efeat, erbf);
    k_embed<<<TN, 256, 0, stream>>>(nodes, embed, x, xb);
    {
        const int total = Ll * 256 * EKPAD + 5 * Ll * 256 * 256 + 256 * 256;
        k_wprep<<<total / 256, 256, 0, stream>>>(me_w1, me_w2, mn_w1, mn_w2, st_w1, st_w2, ro_w1,
                                                 me1T, me2T, mn1T, mn2T, st1T, st2T, ro1T);
    }

    const dim3 gE(2, TE / 128), gN(2, TN / 128), blk(256);
    for (int i = 0; i < Ll; ++i) {
        gemm_k<1, 0><<<gE, blk, 0, stream>>>(erbf, me1T + i * 256 * EKPAD, me_b1 + i * 256,
                                             tedg, nullptr, nullptr, nullptr, TE, 256, EKPAD);
        gemm_k<0, 0><<<gE, blk, 0, stream>>>(tedg, me2T + i * 65536, me_b2 + i * 256,
                                             gate, nullptr, nullptr, nullptr, TE, 256, 256);
        gemm_k<1, 0><<<gN, blk, 0, stream>>>(xb, mn1T + i * 65536, mn_b1 + i * 256,
                                             tmpb, nullptr, nullptr, nullptr, TN, 256, 256);
        gemm_k<0, 1><<<gN, blk, 0, stream>>>(tmpb, mn2T + i * 65536, mn_b2 + i * 256,
                                             nullptr, nmsg, nullptr, nullptr, TN, 256, 256);
        k_agg<<<TN, 256, 0, stream>>>(nmsg, gate, gsrc, coff, eidl, msum);
        gemm_k<1, 0><<<gN, blk, 0, stream>>>(msum, st1T + i * 65536, st_b1 + i * 256,
                                             tmpb, nullptr, nullptr, nullptr, TN, 256, 256);
        gemm_k<0, 2><<<gN, blk, 0, stream>>>(tmpb, st2T + i * 65536, st_b2 + i * 256,
                                             nullptr, nullptr, x, xb, TN, 256, 256);
    }

    gemm_k<1, 0><<<gN, blk, 0, stream>>>(xb, ro1T, ro_b1, tmpb, nullptr, nullptr, nullptr, TN, 256, 256);
    k_readout<<<Bb, 256, 0, stream>>>(tmpb, ro_w2, ro_b2, num_nodes, ev_w, ev_b, out);
}

// Round 2
// 1438.326 us; speedup vs baseline: 1.1034x; 1.1034x over previous
//
#include <hip/hip_runtime.h>

#define Bb 64
#define Nn 128
#define Ee 2048
#define Hh 256
#define Ll 6
#define TN 8192
#define TE 131072
#define EDGE 50
#define EKPAD 64

typedef __attribute__((ext_vector_type(4))) float f32x4;
typedef __attribute__((ext_vector_type(8))) __bf16 bf16x8;

__device__ inline float b2f(unsigned short u) {
    union { unsigned u; float f; } v; v.u = ((unsigned)u) << 16; return v.f;
}
__device__ inline unsigned short f2b(float f) {
    union { float f; unsigned u; } v; v.f = f;
    unsigned r = v.u + 0x7fffu + ((v.u >> 16) & 1u);
    return (unsigned short)(r >> 16);
}
__device__ inline float spf(float x) {   // softplus, stable
    return fmaxf(x, 0.f) + log1pf(expf(-fabsf(x)));
}
__device__ inline float sspf(float x) {  // shifted softplus
    return spf(x) - 0.69314718055994530942f;
}

// ---------------- GEMM: C = act(A @ WT^T + bias) ----------------
// A: M x K bf16 row-major.  WT: N x K bf16 row-major (pre-transposed weight).
// global_load_lds(16B) staging, BK=64, source-side XOR swizzle (slot ^ row&7)
// matched by the same involution on ds_read (rule #21: both-sides-or-neither).
// OUTMODE 0: write bf16 Cb. 2: x-update: Xf += v, Xb = bf16(Xf).
template <int ACT, int OUTMODE, int TM>
__global__ __launch_bounds__(256)
void gemm_k(const unsigned short* __restrict__ A,
            const unsigned short* __restrict__ WT,
            const float* __restrict__ bias,
            unsigned short* __restrict__ Cb,
            float* __restrict__ Xf,
            unsigned short* __restrict__ Xb,
            int M, int N, int K)
{
    constexpr int BK = 64;      // k-elems per LDS tile (128B rows)
    constexpr int TNc = 128;    // col tile
    constexpr int MR = TM / 32; // 16-row fragments per wave (4 or 2)
    constexpr int NR = 4;

    __shared__ unsigned short As[TM * BK];
    __shared__ unsigned short Bs[TNc * BK];

    const int tid  = threadIdx.x;
    const int lane = tid & 63;
    const int w    = tid >> 6;           // wave 0..3
    const int wr   = w >> 1, wc = w & 1; // 2x2 wave grid
    const int r16  = lane & 15;
    const int kg   = lane >> 4;

    const long brow = (long)blockIdx.y * TM;
    const int  bcol = blockIdx.x * TNc;

    // staging geometry: 1KB chunks = 8 rows x 128B; HW writes base + lane*16.
    constexpr int ACH = TM / 8;          // A chunks
    constexpr int NCH = ACH + TNc / 8;   // total chunks (32 or 24)
    constexpr int IPW = NCH / 4;         // issues per wave (8 or 6)
    const int lrow  = lane >> 3;         // row within chunk
    const int lslot = lane & 7;          // 16B slot within row

    f32x4 acc[MR][NR];
#pragma unroll
    for (int m = 0; m < MR; ++m)
#pragma unroll
        for (int n = 0; n < NR; ++n) acc[m][n] = f32x4{0.f, 0.f, 0.f, 0.f};

    for (int k0 = 0; k0 < K; k0 += BK) {
        __syncthreads();   // previous tile's ds_reads complete before overwrite
#pragma unroll
        for (int i = 0; i < IPW; ++i) {
            const int c    = w * IPW + i;
            const bool isA = c < ACH;
            const int cc   = isA ? c : c - ACH;
            const int srow = cc * 8 + lrow;
            const int kch  = lslot ^ (srow & 7);   // inverse-swizzled SOURCE
            const unsigned short* gp = isA
                ? A  + (brow + srow) * (long)K + k0 + kch * 8
                : WT + (bcol + srow) * (long)K + k0 + kch * 8;
            unsigned short* lp = (isA ? As : Bs) + cc * 512;  // wave-uniform base
            __builtin_amdgcn_global_load_lds(
                (const __attribute__((address_space(1))) void*)gp,
                (__attribute__((address_space(3))) void*)lp, 16, 0, 0);
        }
        __syncthreads();   // drains vmcnt(0): staged data visible

        bf16x8 a[MR][2], b[NR][2];
#pragma unroll
        for (int m = 0; m < MR; ++m) {
            const int row = wr * (MR * 16) + m * 16 + r16;
            const unsigned short* base = As + row * BK;
#pragma unroll
            for (int kk = 0; kk < 2; ++kk) {
                const int slot = (kk * 4 + kg) ^ (row & 7);   // swizzled READ
                a[m][kk] = *(const bf16x8*)(base + slot * 8);
            }
        }
#pragma unroll
        for (int n = 0; n < NR; ++n) {
            const int row = wc * 64 + n * 16 + r16;
            const unsigned short* base = Bs + row * BK;
#pragma unroll
            for (int kk = 0; kk < 2; ++kk) {
                const int slot = (kk * 4 + kg) ^ (row & 7);
                b[n][kk] = *(const bf16x8*)(base + slot * 8);
            }
        }
#pragma unroll
        for (int kk = 0; kk < 2; ++kk)
#pragma unroll
            for (int m = 0; m < MR; ++m)
#pragma unroll
                for (int n = 0; n < NR; ++n)
                    acc[m][n] = __builtin_amdgcn_mfma_f32_16x16x32_bf16(
                        a[m][kk], b[n][kk], acc[m][n], 0, 0, 0);
    }

    // epilogue: C row = (lane>>4)*4 + j, col = lane&15 (m89-verified layout)
#pragma unroll
    for (int m = 0; m < MR; ++m) {
#pragma unroll
        for (int n = 0; n < NR; ++n) {
            const int col = bcol + wc * 64 + n * 16 + r16;
            const float bv = bias[col];
#pragma unroll
            for (int j = 0; j < 4; ++j) {
                const long row = brow + wr * (MR * 16) + m * 16 + kg * 4 + j;
                float v = acc[m][n][j] + bv;
                if (ACT) v = sspf(v);
                const long idx = row * (long)N + col;
                if (OUTMODE == 0) {
                    Cb[idx] = f2b(v);
                } else {
                    float nx = Xf[idx] + v;
                    Xf[idx] = nx;
                    Xb[idx] = f2b(nx);
                }
            }
        }
    }
}

// ---------------- small kernels ----------------
__global__ void k_offsets(const int* __restrict__ num_nodes, int* __restrict__ off) {
    __shared__ int s[Bb];
    int t = threadIdx.x;
    s[t] = num_nodes[t];
    __syncthreads();
    for (int d = 1; d < Bb; d <<= 1) {
        int v = (t >= d) ? s[t - d] : 0;
        __syncthreads();
        s[t] += v;
        __syncthreads();
    }
    off[t + 1] = s[t];
    if (t == 0) off[0] = 0;
}

__global__ void k_edgeprep(const int* __restrict__ edges, const int* __restrict__ off,
                           int* __restrict__ gsrc, int* __restrict__ gdst, int* __restrict__ cnt) {
    int ge = blockIdx.x * 256 + threadIdx.x;
    if (ge >= TE) return;
    int b = ge >> 11;                     // E = 2048
    int o = off[b];
    gsrc[ge] = edges[ge * 2 + 0] + o;
    int d = edges[ge * 2 + 1] + o;
    gdst[ge] = d;
    atomicAdd(&cnt[d], 1);
}

__global__ void k_scan(const int* __restrict__ cnt, int* __restrict__ coff, int* __restrict__ pos) {
    __shared__ int part[1024];
    int t = threadIdx.x;
    int loc[8];
    int s = 0;
#pragma unroll
    for (int j = 0; j < 8; ++j) { loc[j] = cnt[t * 8 + j]; s += loc[j]; }
    part[t] = s;
    __syncthreads();
    for (int d = 1; d < 1024; d <<= 1) {
        int v = (t >= d) ? part[t - d] : 0;
        __syncthreads();
        part[t] += v;
        __syncthreads();
    }
    int base = part[t] - s;   // exclusive
#pragma unroll
    for (int j = 0; j < 8; ++j) {
        int idx = t * 8 + j;
        coff[idx] = base;
        pos[idx]  = base;
        base += loc[j];
    }
    if (t == 1023) coff[TN] = part[1023];
}

__global__ void k_fill(const int* __restrict__ gdst, const int* __restrict__ gsrc,
                       int* __restrict__ pos, int* __restrict__ eidl, int* __restrict__ gsrcs) {
    int ge = blockIdx.x * 256 + threadIdx.x;
    if (ge >= TE) return;
    int p = atomicAdd(&pos[gdst[ge]], 1);
    eidl[p]  = ge;
    gsrcs[p] = gsrc[ge];
}

__global__ void k_rbf(const float* __restrict__ ef, unsigned short* __restrict__ erbf) {
    int gid = blockIdx.x * 256 + threadIdx.x;   // TE * 64
    int ge = gid >> 6, k = gid & 63;
    float v = 0.f;
    if (k < EDGE) {
        float d = ef[ge];
        float t = d - 0.1f * (float)k;
        v = expf(-50.f * t * t);
    }
    erbf[gid] = f2b(v);
}

__global__ void k_embed(const int* __restrict__ nodes, const float* __restrict__ embed,
                        float* __restrict__ x, unsigned short* __restrict__ xb) {
    int gid = blockIdx.x * 256 + threadIdx.x;   // TN * 256
    int i = gid >> 8, c = gid & 255;
    float v = embed[(nodes[i] << 8) + c];
    x[gid] = v;
    xb[gid] = f2b(v);
}

// convert + transpose all weights to bf16 N x K
__global__ void k_wprep(const float* __restrict__ me_w1, const float* __restrict__ me_w2,
                        const float* __restrict__ mn_w1, const float* __restrict__ mn_w2,
                        const float* __restrict__ st_w1, const float* __restrict__ st_w2,
                        const float* __restrict__ ro_w1,
                        unsigned short* __restrict__ me1T, unsigned short* __restrict__ me2T,
                        unsigned short* __restrict__ mn1T, unsigned short* __restrict__ mn2T,
                        unsigned short* __restrict__ st1T, unsigned short* __restrict__ st2T,
                        unsigned short* __restrict__ ro1T) {
    int gid = blockIdx.x * 256 + threadIdx.x;
    const int S1 = Ll * 256 * EKPAD;          // me_w1T (padded K)
    if (gid < S1) {
        int i = gid / (256 * EKPAD);
        int r = gid % (256 * EKPAD);
        int n = r / EKPAD, k = r % EKPAD;
        float v = (k < EDGE) ? me_w1[(i * EDGE + k) * 256 + n] : 0.f;
        me1T[gid] = f2b(v);
        return;
    }
    gid -= S1;
    const int S2 = Ll * 256 * 256;
    const float* srcs[5] = { me_w2, mn_w1, mn_w2, st_w1, st_w2 };
    unsigned short* dsts[5] = { me2T, mn1T, mn2T, st1T, st2T };
#pragma unroll
    for (int q = 0; q < 5; ++q) {
        if (gid < S2) {
            int i = gid >> 16;
            int r = gid & 65535;
            int n = r >> 8, k = r & 255;
            dsts[q][gid] = f2b(srcs[q][(i << 16) + k * 256 + n]);
            return;
        }
        gid -= S2;
    }
    // ro_w1T: 256x256
    int n = gid >> 8, k = gid & 255;
    ro1T[gid] = f2b(ro_w1[k * 256 + n]);
}

__global__ void k_agg(const unsigned short* __restrict__ nmsgb, const unsigned short* __restrict__ gates,
                      const int* __restrict__ coff, const int* __restrict__ gsrcs,
                      const int* __restrict__ eidl, unsigned short* __restrict__ msum) {
    int n = blockIdx.x, c = threadIdx.x;
    float s = 0.f;
    int beg = coff[n], end = coff[n + 1];
    for (int i = beg; i < end; ++i) {
        int e  = eidl[i];    // independent loads: no dependent chain
        int sr = gsrcs[i];
        s += b2f(nmsgb[(sr << 8) + c]) * b2f(gates[(e << 8) + c]);
    }
    msum[(n << 8) + c] = f2b(s);
}

__global__ void k_readout(const unsigned short* __restrict__ t, const float* __restrict__ w2,
                          const float* __restrict__ b2, const int* __restrict__ num_nodes,
                          const float* __restrict__ evw, const float* __restrict__ evb,
                          float* __restrict__ out) {
    __shared__ float red[256];
    int b = blockIdx.x, tid = threadIdx.x;
    const unsigned short* tb = t + (long)b * Nn * 256;
    float part = 0.f;
    for (int i = tid; i < Nn * 256; i += 256)
        part += b2f(tb[i]) * w2[i & 255];
    red[tid] = part;
    __syncthreads();
    for (int d = 128; d > 0; d >>= 1) {
        if (tid < d) red[tid] += red[tid + d];
        __syncthreads();
    }
    if (tid == 0) {
        float g = red[0] + (float)Nn * b2[0];
        g = g * 2.0f + (-1.5f) * (float)num_nodes[b];
        out[b * 4 + 0] = g * evw[0] + evb[0];
        out[b * 4 + 1] = spf(g * evw[1] + evb[1]);
        out[b * 4 + 2] = spf(g * evw[2] + evb[2]) + 1.f;
        out[b * 4 + 3] = spf(g * evw[3] + evb[3]);
    }
}

// ---------------- workspace layout ----------------
constexpr size_t al(size_t x) { return (x + 255) & ~(size_t)255; }
constexpr size_t O_OFF   = 0;
constexpr size_t O_GSRC  = al(O_OFF + 65 * 4);
constexpr size_t O_GDST  = al(O_GSRC + (size_t)TE * 4);
constexpr size_t O_CNT   = al(O_GDST + (size_t)TE * 4);
constexpr size_t O_COFF  = al(O_CNT + (size_t)TN * 4);
constexpr size_t O_POS   = al(O_COFF + (size_t)(TN + 1) * 4);
constexpr size_t O_EIDL  = al(O_POS + (size_t)TN * 4);
constexpr size_t O_GSRCS = al(O_EIDL + (size_t)TE * 4);
constexpr size_t O_ERBF  = al(O_GSRCS + (size_t)TE * 4);
constexpr size_t O_ME1T  = al(O_ERBF + (size_t)TE * EKPAD * 2);
constexpr size_t O_ME2T  = al(O_ME1T + (size_t)Ll * 256 * EKPAD * 2);
constexpr size_t O_MN1T  = al(O_ME2T + (size_t)Ll * 256 * 256 * 2);
constexpr size_t O_MN2T  = al(O_MN1T + (size_t)Ll * 256 * 256 * 2);
constexpr size_t O_ST1T  = al(O_MN2T + (size_t)Ll * 256 * 256 * 2);
constexpr size_t O_ST2T  = al(O_ST1T + (size_t)Ll * 256 * 256 * 2);
constexpr size_t O_RO1T  = al(O_ST2T + (size_t)Ll * 256 * 256 * 2);
constexpr size_t O_X     = al(O_RO1T + (size_t)256 * 256 * 2);
constexpr size_t O_XB    = al(O_X + (size_t)TN * 256 * 4);
constexpr size_t O_TMPB  = al(O_XB + (size_t)TN * 256 * 2);
constexpr size_t O_NMSG  = al(O_TMPB + (size_t)TN * 256 * 2);
constexpr size_t O_MSUM  = al(O_NMSG + (size_t)TN * 256 * 2);
constexpr size_t O_TEDG  = al(O_MSUM + (size_t)TN * 256 * 2);
constexpr size_t O_GATE  = al(O_TEDG + (size_t)TE * 256 * 2);
constexpr size_t WS_NEED = al(O_GATE + (size_t)TE * 256 * 2);

extern "C" void kernel_launch(void* const* d_in, const int* in_sizes, int n_in,
                              void* d_out, int out_size, void* d_ws, size_t ws_size,
                              hipStream_t stream) {
    if (ws_size < WS_NEED) return;   // distinguishable failure signature (zeros)

    const int*   nodes     = (const int*)d_in[0];
    const int*   num_nodes = (const int*)d_in[1];
    const int*   edges     = (const int*)d_in[2];
    const float* efeat     = (const float*)d_in[3];
    const float* embed     = (const float*)d_in[5];
    const float* me_w1 = (const float*)d_in[6],  *me_b1 = (const float*)d_in[7];
    const float* me_w2 = (const float*)d_in[8],  *me_b2 = (const float*)d_in[9];
    const float* mn_w1 = (const float*)d_in[10], *mn_b1 = (const float*)d_in[11];
    const float* mn_w2 = (const float*)d_in[12], *mn_b2 = (const float*)d_in[13];
    const float* st_w1 = (const float*)d_in[14], *st_b1 = (const float*)d_in[15];
    const float* st_w2 = (const float*)d_in[16], *st_b2 = (const float*)d_in[17];
    const float* ro_w1 = (const float*)d_in[18], *ro_b1 = (const float*)d_in[19];
    const float* ro_w2 = (const float*)d_in[20], *ro_b2 = (const float*)d_in[21];
    const float* ev_w  = (const float*)d_in[22], *ev_b  = (const float*)d_in[23];

    char* ws = (char*)d_ws;
    int* off   = (int*)(ws + O_OFF);
    int* gsrc  = (int*)(ws + O_GSRC);
    int* gdst  = (int*)(ws + O_GDST);
    int* cnt   = (int*)(ws + O_CNT);
    int* coff  = (int*)(ws + O_COFF);
    int* pos   = (int*)(ws + O_POS);
    int* eidl  = (int*)(ws + O_EIDL);
    int* gsrcs = (int*)(ws + O_GSRCS);
    unsigned short* erbf  = (unsigned short*)(ws + O_ERBF);
    unsigned short* me1T  = (unsigned short*)(ws + O_ME1T);
    unsigned short* me2T  = (unsigned short*)(ws + O_ME2T);
    unsigned short* mn1T  = (unsigned short*)(ws + O_MN1T);
    unsigned short* mn2T  = (unsigned short*)(ws + O_MN2T);
    unsigned short* st1T  = (unsigned short*)(ws + O_ST1T);
    unsigned short* st2T  = (unsigned short*)(ws + O_ST2T);
    unsigned short* ro1T  = (unsigned short*)(ws + O_RO1T);
    float*          x     = (float*)(ws + O_X);
    unsigned short* xb    = (unsigned short*)(ws + O_XB);
    unsigned short* tmpb  = (unsigned short*)(ws + O_TMPB);
    unsigned short* nmsgb = (unsigned short*)(ws + O_NMSG);
    unsigned short* msum  = (unsigned short*)(ws + O_MSUM);
    unsigned short* tedg  = (unsigned short*)(ws + O_TEDG);
    unsigned short* gate  = (unsigned short*)(ws + O_GATE);
    float* out = (float*)d_out;

    hipMemsetAsync(cnt, 0, TN * 4, stream);
    k_offsets<<<1, Bb, 0, stream>>>(num_nodes, off);
    k_edgeprep<<<TE / 256, 256, 0, stream>>>(edges, off, gsrc, gdst, cnt);
    k_scan<<<1, 1024, 0, stream>>>(cnt, coff, pos);
    k_fill<<<TE / 256, 256, 0, stream>>>(gdst, gsrc, pos, eidl, gsrcs);
    k_rbf<<<(TE * EKPAD) / 256, 256, 0, stream>>>(efeat, erbf);
    k_embed<<<TN, 256, 0, stream>>>(nodes, embed, x, xb);
    {
        const int total = Ll * 256 * EKPAD + 5 * Ll * 256 * 256 + 256 * 256;
        k_wprep<<<total / 256, 256, 0, stream>>>(me_w1, me_w2, mn_w1, mn_w2, st_w1, st_w2, ro_w1,
                                                 me1T, me2T, mn1T, mn2T, st1T, st2T, ro1T);
    }

    const dim3 gE(2, TE / 128), gN(2, TN / 64), blk(256);
    for (int i = 0; i < Ll; ++i) {
        gemm_k<1, 0, 128><<<gE, blk, 0, stream>>>(erbf, me1T + i * 256 * EKPAD, me_b1 + i * 256,
                                                  tedg, nullptr, nullptr, TE, 256, EKPAD);
        gemm_k<0, 0, 128><<<gE, blk, 0, stream>>>(tedg, me2T + i * 65536, me_b2 + i * 256,
                                                  gate, nullptr, nullptr, TE, 256, 256);
        gemm_k<1, 0, 64><<<gN, blk, 0, stream>>>(xb, mn1T + i * 65536, mn_b1 + i * 256,
                                                 tmpb, nullptr, nullptr, TN, 256, 256);
        gemm_k<0, 0, 64><<<gN, blk, 0, stream>>>(tmpb, mn2T + i * 65536, mn_b2 + i * 256,
                                                 nmsgb, nullptr, nullptr, TN, 256, 256);
        k_agg<<<TN, 256, 0, stream>>>(nmsgb, gate, coff, gsrcs, eidl, msum);
        gemm_k<1, 0, 64><<<gN, blk, 0, stream>>>(msum, st1T + i * 65536, st_b1 + i * 256,
                                                 tmpb, nullptr, nullptr, TN, 256, 256);
        gemm_k<0, 2, 64><<<gN, blk, 0, stream>>>(tmpb, st2T + i * 65536, st_b2 + i * 256,
                                                 nullptr, x, xb, TN, 256, 256);
    }

    gemm_k<1, 0, 64><<<gN, blk, 0, stream>>>(xb, ro1T, ro_b1, tmpb, nullptr, nullptr, TN, 256, 256);
    k_readout<<<Bb, 256, 0, stream>>>(tmpb, ro_w2, ro_b2, num_nodes, ev_w, ev_b, out);
}